// Round 3
// baseline (391.836 us; speedup 1.0000x reference)
//
#include <hip/hip_runtime.h>

#define NSAMP  65536
#define LATENT 64
#define OUTF   128
#define H1N    32
#define H2N    32

// Block: 256 threads = 4 waves. Each block: 64 samples x all 128 features.
// Thread (s = t&63, wave w = t>>6) handles sample s, features [32w, 32w+32).
// d is wave-uniform -> all weight loads are scalar (s_load), VALU does pure FMA.
__global__ __launch_bounds__(256) void decoder_kernel(
    const float* __restrict__ z,  const float* __restrict__ Wp,
    const float* __restrict__ W1, const float* __restrict__ b1,
    const float* __restrict__ W2, const float* __restrict__ b2,
    const float* __restrict__ W3, const float* __restrict__ b3,
    float* __restrict__ out)
{
    __shared__ float zt[64][LATENT + 1];   // +1 pad: kill stride-64 bank conflict
    __shared__ float xt[64][OUTF + 1];     // +1 pad: conflict-free transposed write

    const int t  = threadIdx.x;
    const int s  = t & 63;
    const int w  = __builtin_amdgcn_readfirstlane(t >> 6);  // force wave-uniform
    const int n0 = blockIdx.x * 64;

    // ---- stage z tile: 64 samples x 64 latent = contiguous 16KB ----
    const float4* zsrc = (const float4*)(z + (size_t)n0 * LATENT);
    for (int i = t; i < 64 * (LATENT / 4); i += 256) {
        float4 v = zsrc[i];
        int row = i >> 4;
        int col = (i & 15) << 2;
        zt[row][col + 0] = v.x; zt[row][col + 1] = v.y;
        zt[row][col + 2] = v.z; zt[row][col + 3] = v.w;
    }
    __syncthreads();

    // z row of this thread's sample -> registers (reused for 32 features)
    float zr[LATENT];
    #pragma unroll
    for (int l = 0; l < LATENT; ++l) zr[l] = zt[s][l];

    #pragma unroll 1      // keep loop rolled: body ~1.2k instrs, fits I-cache
    for (int j = 0; j < 32; ++j) {
        const int d = w * 32 + j;            // wave-uniform feature index

        // ---- y = z . |Wp[d]|  (4 independent chains) ----
        const float* wp = Wp + d * LATENT;
        float a0 = 0.f, a1 = 0.f, a2 = 0.f, a3 = 0.f;
        #pragma unroll
        for (int l = 0; l < LATENT; l += 4) {
            a0 += zr[l]     * fabsf(wp[l]);
            a1 += zr[l + 1] * fabsf(wp[l + 1]);
            a2 += zr[l + 2] * fabsf(wp[l + 2]);
            a3 += zr[l + 3] * fabsf(wp[l + 3]);
        }
        const float yv = (a0 + a1) + (a2 + a3);

        // ---- layer 1: 1 -> 32, relu ----
        const float* w1  = W1 + d * H1N;
        const float* bb1 = b1 + d * H1N;
        float h1[H1N];
        #pragma unroll
        for (int h = 0; h < H1N; ++h)
            h1[h] = fmaxf(yv * w1[h] + bb1[h], 0.f);

        // ---- layer 2 (32x32) + layer 3 folded in ----
        const float* w2  = W2 + d * H2N * H1N;
        const float* bb2 = b2 + d * H2N;
        const float* w3  = W3 + d * H2N;
        float xa0 = 0.f, xa1 = 0.f, xa2 = 0.f, xa3 = 0.f;
        #pragma unroll
        for (int k = 0; k < H2N; k += 4) {   // 4 independent FMA chains
            float c0 = bb2[k],     c1 = bb2[k + 1];
            float c2 = bb2[k + 2], c3 = bb2[k + 3];
            const float* r0 = w2 + k * H1N;
            const float* r1 = r0 + H1N;
            const float* r2 = r1 + H1N;
            const float* r3 = r2 + H1N;
            #pragma unroll
            for (int h = 0; h < H1N; ++h) {
                c0 += h1[h] * r0[h];
                c1 += h1[h] * r1[h];
                c2 += h1[h] * r2[h];
                c3 += h1[h] * r3[h];
            }
            xa0 += fmaxf(c0, 0.f) * w3[k];
            xa1 += fmaxf(c1, 0.f) * w3[k + 1];
            xa2 += fmaxf(c2, 0.f) * w3[k + 2];
            xa3 += fmaxf(c3, 0.f) * w3[k + 3];
        }
        const float xv = (xa0 + xa1) + (xa2 + xa3) + b3[d];
        xt[s][d] = fabsf(xv);                // banks (s + d) % 32: conflict-free
    }
    __syncthreads();

    // ---- coalesced store of the [64][128] output tile ----
    float* dst = out + (size_t)n0 * OUTF;
    for (int i = t; i < 64 * OUTF; i += 256)
        dst[i] = xt[i >> 7][i & 127];
}

extern "C" void kernel_launch(void* const* d_in, const int* in_sizes, int n_in,
                              void* d_out, int out_size, void* d_ws, size_t ws_size,
                              hipStream_t stream) {
    const float* z  = (const float*)d_in[0];
    const float* Wp = (const float*)d_in[1];
    const float* W1 = (const float*)d_in[2];
    const float* b1 = (const float*)d_in[3];
    const float* W2 = (const float*)d_in[4];
    const float* b2 = (const float*)d_in[5];
    const float* W3 = (const float*)d_in[6];
    const float* b3 = (const float*)d_in[7];
    float* out = (float*)d_out;

    dim3 grid(NSAMP / 64);
    dim3 block(256);
    hipLaunchKernelGGL(decoder_kernel, grid, block, 0, stream,
                       z, Wp, W1, b1, W2, b2, W3, b3, out);
}

// Round 4
// 121.006 us; speedup vs baseline: 3.2382x; 3.2382x over previous
//
#include <hip/hip_runtime.h>

typedef unsigned int uint32;
typedef __attribute__((ext_vector_type(8))) short bf16x8;
typedef __attribute__((ext_vector_type(4))) float f32x4;

#define MFMA(A, B, C) __builtin_amdgcn_mfma_f32_16x16x32_bf16(A, B, C, 0, 0, 0)

union FragU { uint32 u[4]; bf16x8 v; };

// Split 8 fp32 into hi/lo bf16 fragments (truncation split: hi=top16, lo=bf16(x-hi)).
// Exact products in MFMA (bf16*bf16 exact in fp32 accum) -> ~2^-16 rel error total.
__device__ __forceinline__ void split8(f32x4 a, f32x4 b, bf16x8& hi, bf16x8& lo) {
    float e[8] = {a[0], a[1], a[2], a[3], b[0], b[1], b[2], b[3]};
    FragU H, L;
    #pragma unroll
    for (int q = 0; q < 4; ++q) {
        uint32 u0 = __float_as_uint(e[2*q]);
        uint32 u1 = __float_as_uint(e[2*q + 1]);
        uint32 h0 = u0 & 0xFFFF0000u;
        uint32 h1 = u1 & 0xFFFF0000u;
        float l0 = e[2*q]     - __uint_as_float(h0);
        float l1 = e[2*q + 1] - __uint_as_float(h1);
        H.u[q] = (h0 >> 16) | h1;
        L.u[q] = (__float_as_uint(l0) >> 16) | (__float_as_uint(l1) & 0xFFFF0000u);
    }
    hi = H.v; lo = L.v;
}

// 256 thr = 4 waves. Block: 64 samples x 128 features; wave wv owns features [32wv, 32wv+32).
// Phase 1: Y = z @ |Wp|^T  (split-bf16 3-pass MFMA) -> wave-private LDS Y[64][33].
// Phase 2: per d: layer1 in-lane (B-frag layout), layer2 swapped MFMA (A=W2 rows,
//          B=h1 cols) so k2 lands in-lane; layer3 = in-lane relu*W3 + shfl_xor(16,32).
__global__ __launch_bounds__(256) void decoder_mfma(
    const float* __restrict__ z,  const float* __restrict__ Wp,
    const float* __restrict__ W1, const float* __restrict__ b1,
    const float* __restrict__ W2, const float* __restrict__ b2,
    const float* __restrict__ W3, const float* __restrict__ b3,
    float* __restrict__ out)
{
    __shared__ float Y[4][64][33];   // 33.8 KB, +1 pad: conflict-free col reads

    const int t    = threadIdx.x;
    const int lane = t & 63;
    const int wv   = __builtin_amdgcn_readfirstlane(t >> 6);
    const int l15  = lane & 15;
    const int lg   = lane >> 4;          // 0..3
    const int n0   = blockIdx.x * 64;

    // ---------------- Phase 1: Y = z @ |Wp|^T -----------------------------
    bf16x8 wh[2][2], wl[2][2];           // [dtile][ktile]
    #pragma unroll
    for (int dt = 0; dt < 2; ++dt) {
        const int d = wv*32 + dt*16 + l15;        // B-frag col
        #pragma unroll
        for (int kt = 0; kt < 2; ++kt) {
            const float* p = Wp + d*64 + kt*32 + lg*8;   // 8 contiguous k
            f32x4 a = *(const f32x4*)p;
            f32x4 b = *(const f32x4*)(p + 4);
            #pragma unroll
            for (int i = 0; i < 4; ++i) { a[i] = fabsf(a[i]); b[i] = fabsf(b[i]); }
            split8(a, b, wh[dt][kt], wl[dt][kt]);
        }
    }
    #pragma unroll
    for (int nt = 0; nt < 4; ++nt) {
        bf16x8 zh[2], zl[2];
        #pragma unroll
        for (int kt = 0; kt < 2; ++kt) {
            const float* p = z + (size_t)(n0 + nt*16 + l15)*64 + kt*32 + lg*8;
            split8(*(const f32x4*)p, *(const f32x4*)(p + 4), zh[kt], zl[kt]);
        }
        #pragma unroll
        for (int dt = 0; dt < 2; ++dt) {
            f32x4 acc = {0.f, 0.f, 0.f, 0.f};
            #pragma unroll
            for (int kt = 0; kt < 2; ++kt) {
                acc = MFMA(zh[kt], wh[dt][kt], acc);   // hi*hi
                acc = MFMA(zl[kt], wh[dt][kt], acc);   // lo*hi
                acc = MFMA(zh[kt], wl[dt][kt], acc);   // hi*lo
            }
            // D: row n = lg*4+r, col d = l15
            #pragma unroll
            for (int r = 0; r < 4; ++r)
                Y[wv][nt*16 + lg*4 + r][dt*16 + l15] = acc[r];
        }
    }
    __syncthreads();

    // ---------------- Phase 2: per-feature tiny MLP -----------------------
    #pragma unroll 1
    for (int j = 0; j < 32; ++j) {
        const int d = wv*32 + j;                 // wave-uniform feature
        // A-frags: W2[d] rows (k2 = rt*16 + l15), k-dim = h = lg*8 + i
        bf16x8 ah[2], al[2];
        #pragma unroll
        for (int rt = 0; rt < 2; ++rt) {
            const float* p = W2 + (size_t)d*1024 + (rt*16 + l15)*32 + lg*8;
            split8(*(const f32x4*)p, *(const f32x4*)(p + 4), ah[rt], al[rt]);
        }
        const f32x4 w1a = *(const f32x4*)(W1 + d*32 + lg*8);
        const f32x4 w1b = *(const f32x4*)(W1 + d*32 + lg*8 + 4);
        const f32x4 b1a = *(const f32x4*)(b1 + d*32 + lg*8);
        const f32x4 b1b = *(const f32x4*)(b1 + d*32 + lg*8 + 4);
        const f32x4 b2a = *(const f32x4*)(b2 + d*32 + lg*4);        // k2 = lg*4+r
        const f32x4 b2b = *(const f32x4*)(b2 + d*32 + 16 + lg*4);
        const f32x4 w3a = *(const f32x4*)(W3 + d*32 + lg*4);
        const f32x4 w3b = *(const f32x4*)(W3 + d*32 + 16 + lg*4);
        const float b3v = b3[d];

        #pragma unroll
        for (int ct = 0; ct < 4; ++ct) {
            // layer 1: lane computes h1 of sample n = ct*16+l15 at h = lg*8..+7
            const float y = Y[wv][ct*16 + l15][j];
            f32x4 h0, h1v;
            #pragma unroll
            for (int i = 0; i < 4; ++i) h0[i]  = fmaxf(y*w1a[i] + b1a[i], 0.f);
            #pragma unroll
            for (int i = 0; i < 4; ++i) h1v[i] = fmaxf(y*w1b[i] + b1b[i], 0.f);
            bf16x8 bh, bl;
            split8(h0, h1v, bh, bl);
            // layer 2: D[k2, n] = W2[k2,:] . h1[n,:]   (3-pass split)
            f32x4 a0 = {0.f, 0.f, 0.f, 0.f}, a1 = {0.f, 0.f, 0.f, 0.f};
            a0 = MFMA(ah[0], bh, a0);
            a0 = MFMA(al[0], bh, a0);
            a0 = MFMA(ah[0], bl, a0);
            a1 = MFMA(ah[1], bh, a1);
            a1 = MFMA(al[1], bh, a1);
            a1 = MFMA(ah[1], bl, a1);
            // layer 3: rows k2 = rt*16 + lg*4 + r live in-lane
            float s = 0.f;
            #pragma unroll
            for (int r = 0; r < 4; ++r) {
                s += fmaxf(a0[r] + b2a[r], 0.f) * w3a[r];
                s += fmaxf(a1[r] + b2b[r], 0.f) * w3b[r];
            }
            s += __shfl_xor(s, 16);      // reduce over the 4 lg groups
            s += __shfl_xor(s, 32);
            const float x = fabsf(s + b3v);
            if (lane < 16) Y[wv][ct*16 + lane][j] = x;   // overwrite consumed y
        }
    }
    __syncthreads();

    // ---------------- coalesced copy-out ----------------------------------
    const int cg = lane & 7;
    #pragma unroll
    for (int it = 0; it < 8; ++it) {
        const int n = it*8 + (lane >> 3);
        f32x4 v;
        #pragma unroll
        for (int c = 0; c < 4; ++c) v[c] = Y[wv][n][cg*4 + c];
        *(f32x4*)(out + (size_t)(n0 + n)*128 + wv*32 + cg*4) = v;
    }
}

extern "C" void kernel_launch(void* const* d_in, const int* in_sizes, int n_in,
                              void* d_out, int out_size, void* d_ws, size_t ws_size,
                              hipStream_t stream) {
    const float* z  = (const float*)d_in[0];
    const float* Wp = (const float*)d_in[1];
    const float* W1 = (const float*)d_in[2];
    const float* b1 = (const float*)d_in[3];
    const float* W2 = (const float*)d_in[4];
    const float* b2 = (const float*)d_in[5];
    const float* W3 = (const float*)d_in[6];
    const float* b3 = (const float*)d_in[7];
    float* out = (float*)d_out;

    hipLaunchKernelGGL(decoder_mfma, dim3(65536 / 64), dim3(256), 0, stream,
                       z, Wp, W1, b1, W2, b2, W3, b3, out);
}

// Round 5
// 88.124 us; speedup vs baseline: 4.4464x; 1.3731x over previous
//
#include <hip/hip_runtime.h>
#include <hip/hip_bf16.h>

typedef unsigned int uint32;
typedef __attribute__((ext_vector_type(8))) short bf16x8;
typedef __attribute__((ext_vector_type(4))) float f32x4;

#define MFMA(A, B, C) __builtin_amdgcn_mfma_f32_16x16x32_bf16(A, B, C, 0, 0, 0)

union FragU { uint32 u[4]; bf16x8 v; };
union BF8  { __hip_bfloat162 h2[4]; bf16x8 v; };

// 3-pass split (phase-1 z only): hi=trunc top16, lo=bf16(x-hi)
__device__ __forceinline__ void split8(f32x4 a, f32x4 b, bf16x8& hi, bf16x8& lo) {
    float e[8] = {a[0], a[1], a[2], a[3], b[0], b[1], b[2], b[3]};
    FragU H, L;
    #pragma unroll
    for (int q = 0; q < 4; ++q) {
        uint32 u0 = __float_as_uint(e[2*q]);
        uint32 u1 = __float_as_uint(e[2*q + 1]);
        uint32 h0 = u0 & 0xFFFF0000u;
        uint32 h1 = u1 & 0xFFFF0000u;
        float l0 = e[2*q]     - __uint_as_float(h0);
        float l1 = e[2*q + 1] - __uint_as_float(h1);
        H.u[q] = (h0 >> 16) | h1;
        L.u[q] = (__float_as_uint(l0) >> 16) | (__float_as_uint(l1) & 0xFFFF0000u);
    }
    hi = H.v; lo = L.v;
}

// single-pass RNE pack: 8 f32 -> 8 bf16 (compiler fuses to v_cvt_pk_bf16_f32)
__device__ __forceinline__ bf16x8 pack8(f32x4 a, f32x4 b) {
    BF8 r;
    r.h2[0] = __float22bfloat162_rn(make_float2(a[0], a[1]));
    r.h2[1] = __float22bfloat162_rn(make_float2(a[2], a[3]));
    r.h2[2] = __float22bfloat162_rn(make_float2(b[0], b[1]));
    r.h2[3] = __float22bfloat162_rn(make_float2(b[2], b[3]));
    return r.v;
}

// ---- pre-kernel: split |Wp| and W2 into RNE hi/lo bf16 pairs in d_ws ----
__global__ __launch_bounds__(256) void split_weights(
    const float* __restrict__ Wp, const float* __restrict__ W2,
    __hip_bfloat16* __restrict__ wp_hi, __hip_bfloat16* __restrict__ wp_lo,
    __hip_bfloat16* __restrict__ w2_hi, __hip_bfloat16* __restrict__ w2_lo)
{
    const int i = blockIdx.x * 256 + threadIdx.x;
    if (i < 128 * 64) {
        float x = fabsf(Wp[i]);
        __hip_bfloat16 h = __float2bfloat16(x);          // RNE
        wp_hi[i] = h;
        wp_lo[i] = __float2bfloat16(x - __bfloat162float(h));
    }
    if (i < 128 * 1024) {
        float x = W2[i];
        __hip_bfloat16 h = __float2bfloat16(x);
        w2_hi[i] = h;
        w2_lo[i] = __float2bfloat16(x - __bfloat162float(h));
    }
}

// 256 thr = 4 waves. Block: 64 samples x 128 features; wave wv owns 32 features.
// Phase 1: Y = z @ |Wp|^T (z 3-pass split x pre-split Wp) -> LDS Y[wv][64][33].
// Phase 2: per d: layer1 in-lane (B-frag layout), layer2 = pre-split W2 (A, 2-pass)
//          x RNE-bf16 h1 (B, 1-pass) = 4 MFMA; layer3 in-lane + shfl_xor(16,32).
__global__ __launch_bounds__(256) void decoder_mfma(
    const float* __restrict__ z,
    const __hip_bfloat16* __restrict__ wp_hi, const __hip_bfloat16* __restrict__ wp_lo,
    const __hip_bfloat16* __restrict__ w2_hi, const __hip_bfloat16* __restrict__ w2_lo,
    const float* __restrict__ W1, const float* __restrict__ b1,
    const float* __restrict__ b2,
    const float* __restrict__ W3, const float* __restrict__ b3,
    float* __restrict__ out)
{
    __shared__ float Y[4][64][33];   // 33.8 KB, +1 pad

    const int t    = threadIdx.x;
    const int lane = t & 63;
    const int wv   = __builtin_amdgcn_readfirstlane(t >> 6);
    const int l15  = lane & 15;
    const int lg   = lane >> 4;
    const int n0   = blockIdx.x * 64;

    // ---------------- Phase 1: Y = z @ |Wp|^T -----------------------------
    bf16x8 wh[2][2], wl[2][2];
    #pragma unroll
    for (int dt = 0; dt < 2; ++dt) {
        const int d = wv*32 + dt*16 + l15;
        #pragma unroll
        for (int kt = 0; kt < 2; ++kt) {
            const int off = d*64 + kt*32 + lg*8;
            wh[dt][kt] = *(const bf16x8*)(wp_hi + off);
            wl[dt][kt] = *(const bf16x8*)(wp_lo + off);
        }
    }
    #pragma unroll
    for (int nt = 0; nt < 4; ++nt) {
        bf16x8 zh[2], zl[2];
        #pragma unroll
        for (int kt = 0; kt < 2; ++kt) {
            const float* p = z + (size_t)(n0 + nt*16 + l15)*64 + kt*32 + lg*8;
            split8(*(const f32x4*)p, *(const f32x4*)(p + 4), zh[kt], zl[kt]);
        }
        #pragma unroll
        for (int dt = 0; dt < 2; ++dt) {
            f32x4 acc = {0.f, 0.f, 0.f, 0.f};
            #pragma unroll
            for (int kt = 0; kt < 2; ++kt) {
                acc = MFMA(zh[kt], wh[dt][kt], acc);   // hi*hi
                acc = MFMA(zl[kt], wh[dt][kt], acc);   // lo*hi
                acc = MFMA(zh[kt], wl[dt][kt], acc);   // hi*lo
            }
            #pragma unroll
            for (int r = 0; r < 4; ++r)
                Y[wv][nt*16 + lg*4 + r][dt*16 + l15] = acc[r];
        }
    }
    __syncthreads();

    // ---------------- Phase 2: per-feature tiny MLP -----------------------
    #pragma unroll 1
    for (int j = 0; j < 32; ++j) {
        const int d = wv*32 + j;                 // wave-uniform feature
        // A-frags: pre-split W2[d] rows (k2 = rt*16+l15), k = h = lg*8+i
        bf16x8 ah[2], al[2];
        #pragma unroll
        for (int rt = 0; rt < 2; ++rt) {
            const int off = d*1024 + (rt*16 + l15)*32 + lg*8;
            ah[rt] = *(const bf16x8*)(w2_hi + off);
            al[rt] = *(const bf16x8*)(w2_lo + off);
        }
        const f32x4 w1a = *(const f32x4*)(W1 + d*32 + lg*8);
        const f32x4 w1b = *(const f32x4*)(W1 + d*32 + lg*8 + 4);
        const f32x4 b1a = *(const f32x4*)(b1 + d*32 + lg*8);
        const f32x4 b1b = *(const f32x4*)(b1 + d*32 + lg*8 + 4);
        const f32x4 b2a = *(const f32x4*)(b2 + d*32 + lg*4);
        const f32x4 b2b = *(const f32x4*)(b2 + d*32 + 16 + lg*4);
        const f32x4 w3a = *(const f32x4*)(W3 + d*32 + lg*4);
        const f32x4 w3b = *(const f32x4*)(W3 + d*32 + 16 + lg*4);
        const float b3v = b3[d];

        #pragma unroll
        for (int ct = 0; ct < 4; ++ct) {
            // layer 1: lane -> sample n = ct*16+l15, h = lg*8..+7
            const float y = Y[wv][ct*16 + l15][j];
            f32x4 h0, h1v;
            #pragma unroll
            for (int i = 0; i < 4; ++i) h0[i]  = fmaxf(y*w1a[i] + b1a[i], 0.f);
            #pragma unroll
            for (int i = 0; i < 4; ++i) h1v[i] = fmaxf(y*w1b[i] + b1b[i], 0.f);
            const bf16x8 bh = pack8(h0, h1v);          // single-pass RNE
            // layer 2: D[k2, n] = W2[k2,:] . h1[n,:]  (A 2-pass x B 1-pass)
            f32x4 a0 = {0.f, 0.f, 0.f, 0.f}, a1 = {0.f, 0.f, 0.f, 0.f};
            a0 = MFMA(ah[0], bh, a0);
            a0 = MFMA(al[0], bh, a0);
            a1 = MFMA(ah[1], bh, a1);
            a1 = MFMA(al[1], bh, a1);
            // layer 3: rows k2 = rt*16 + lg*4 + r live in-lane
            float s = 0.f;
            #pragma unroll
            for (int r = 0; r < 4; ++r) {
                s += fmaxf(a0[r] + b2a[r], 0.f) * w3a[r];
                s += fmaxf(a1[r] + b2b[r], 0.f) * w3b[r];
            }
            s += __shfl_xor(s, 16);
            s += __shfl_xor(s, 32);
            const float x = fabsf(s + b3v);
            if (lane < 16) Y[wv][ct*16 + lane][j] = x;
        }
    }
    __syncthreads();

    // ---------------- coalesced copy-out ----------------------------------
    const int cg = lane & 7;
    #pragma unroll
    for (int it = 0; it < 8; ++it) {
        const int n = it*8 + (lane >> 3);
        f32x4 v;
        #pragma unroll
        for (int c = 0; c < 4; ++c) v[c] = Y[wv][n][cg*4 + c];
        *(f32x4*)(out + (size_t)(n0 + n)*128 + wv*32 + cg*4) = v;
    }
}

extern "C" void kernel_launch(void* const* d_in, const int* in_sizes, int n_in,
                              void* d_out, int out_size, void* d_ws, size_t ws_size,
                              hipStream_t stream) {
    const float* z  = (const float*)d_in[0];
    const float* Wp = (const float*)d_in[1];
    const float* W1 = (const float*)d_in[2];
    const float* b1 = (const float*)d_in[3];
    const float* W2 = (const float*)d_in[4];
    const float* b2 = (const float*)d_in[5];
    const float* W3 = (const float*)d_in[6];
    const float* b3 = (const float*)d_in[7];
    float* out = (float*)d_out;

    __hip_bfloat16* wp_hi = (__hip_bfloat16*)d_ws;
    __hip_bfloat16* wp_lo = wp_hi + 128 * 64;
    __hip_bfloat16* w2_hi = wp_lo + 128 * 64;
    __hip_bfloat16* w2_lo = w2_hi + 128 * 1024;

    hipLaunchKernelGGL(split_weights, dim3(512), dim3(256), 0, stream,
                       Wp, W2, wp_hi, wp_lo, w2_hi, w2_lo);
    hipLaunchKernelGGL(decoder_mfma, dim3(65536 / 64), dim3(256), 0, stream,
                       z, wp_hi, wp_lo, w2_hi, w2_lo, W1, b1, b2, W3, b3, out);
}